// Round 1
// baseline (36836.862 us; speedup 1.0000x reference)
//
#include <hip/hip_runtime.h>
#include <hip/hip_bf16.h>
#include <stdint.h>

#define BATCH 4096
#define TT    80
#define EMB   100
#define UNITS 512
#define N4    2048
#define VOCABSZ 10000

// JAX threefry mode: 1 = partitionable (modern default), 0 = original
#define PARTITIONABLE 1

// ---------------- threefry2x32 (20 rounds, JAX-compatible) ----------------
__device__ __forceinline__ uint32_t rotl32(uint32_t x, uint32_t r) {
  return (x << r) | (x >> (32u - r));
}

__device__ __forceinline__ void tf_round4(uint32_t& x0, uint32_t& x1,
                                          int r0, int r1, int r2, int r3) {
  x0 += x1; x1 = rotl32(x1, r0); x1 ^= x0;
  x0 += x1; x1 = rotl32(x1, r1); x1 ^= x0;
  x0 += x1; x1 = rotl32(x1, r2); x1 ^= x0;
  x0 += x1; x1 = rotl32(x1, r3); x1 ^= x0;
}

__device__ __forceinline__ void tf2x32(uint32_t k0, uint32_t k1,
                                       uint32_t x0, uint32_t x1,
                                       uint32_t& y0, uint32_t& y1) {
  uint32_t k2 = k0 ^ k1 ^ 0x1BD11BDAu;
  x0 += k0; x1 += k1;
  tf_round4(x0, x1, 13, 15, 26, 6);  x0 += k1; x1 += k2 + 1u;
  tf_round4(x0, x1, 17, 29, 16, 24); x0 += k2; x1 += k0 + 2u;
  tf_round4(x0, x1, 13, 15, 26, 6);  x0 += k0; x1 += k1 + 3u;
  tf_round4(x0, x1, 17, 29, 16, 24); x0 += k1; x1 += k2 + 4u;
  tf_round4(x0, x1, 13, 15, 26, 6);  x0 += k2; x1 += k0 + 5u;
  y0 = x0; y1 = x1;
}

// uniform-from-bits (JAX float32 path), then bernoulli(0.8) / 0.8
__device__ __forceinline__ float keepval(uint32_t u) {
  float f = __uint_as_float((u >> 9) | 0x3F800000u) - 1.0f;
  return f < 0.8f ? 1.25f : 0.0f;
}

#define M0N (4 * BATCH * EMB)    // 1,638,400
#define M1N (4 * BATCH * UNITS)  // 8,388,608

__global__ __launch_bounds__(256) void masks_kernel(float* __restrict__ m0,
                                                    float* __restrict__ m1) {
#if PARTITIONABLE
  // split(key(42)) fold-like: k_i = E_{(0,42)}(0, i)
  uint32_t k0a, k0b, k1a, k1b;
  tf2x32(0u, 42u, 0u, 0u, k0a, k0b);
  tf2x32(0u, 42u, 0u, 1u, k1a, k1b);
  const int total = M0N + M1N;
  for (int j = blockIdx.x * blockDim.x + threadIdx.x; j < total;
       j += gridDim.x * blockDim.x) {
    if (j < M0N) {
      uint32_t y0, y1;
      tf2x32(k0a, k0b, 0u, (uint32_t)j, y0, y1);
      m0[j] = keepval(y0 ^ y1);
    } else {
      int jj = j - M0N;
      uint32_t y0, y1;
      tf2x32(k1a, k1b, 0u, (uint32_t)jj, y0, y1);
      m1[jj] = keepval(y0 ^ y1);
    }
  }
#else
  // original split: counts [0,1,2,3]; blocks (0,2),(1,3); k0=(E02.0,E13.0), k1=(E02.1,E13.1)
  uint32_t a0, a1, b0, b1;
  tf2x32(0u, 42u, 0u, 2u, a0, a1);
  tf2x32(0u, 42u, 1u, 3u, b0, b1);
  const uint32_t k0a = a0, k0b = b0, k1a = a1, k1b = b1;
  const int H0 = M0N / 2, H1 = M1N / 2;
  const int total = H0 + H1;
  for (int j = blockIdx.x * blockDim.x + threadIdx.x; j < total;
       j += gridDim.x * blockDim.x) {
    if (j < H0) {
      uint32_t y0, y1;
      tf2x32(k0a, k0b, (uint32_t)j, (uint32_t)(j + H0), y0, y1);
      m0[j] = keepval(y0);
      m0[j + H0] = keepval(y1);
    } else {
      int jj = j - H0;
      uint32_t y0, y1;
      tf2x32(k1a, k1b, (uint32_t)jj, (uint32_t)(jj + H1), y0, y1);
      m1[jj] = keepval(y0);
      m1[jj + H1] = keepval(y1);
    }
  }
#endif
}

// ---------------- fused cell GEMM: z = (x .* m_g) @ W + h_prev @ U + b ----
#define BM 64
#define BN 64
#define BK 16

__global__ __launch_bounds__(256) void cell_gemm(
    const float* __restrict__ A1,     // layer1: h0 [B,Kin]; layer0: nullptr
    const int* __restrict__ inputs,   // layer0 gather
    const float* __restrict__ embed,  // layer0 gather
    int t, int Kin,                   // 100 (layer0) or 512 (layer1)
    const float* __restrict__ mask,   // [4][B][Kin]
    const float* __restrict__ W,      // [Kin][2048]
    const float* __restrict__ U,      // [512][2048]
    const float* __restrict__ bias,   // [2048]
    const float* __restrict__ hprev,  // [B][512]
    float* __restrict__ z)            // [B][2048]
{
  __shared__ __align__(16) float As[BK][BM];
  __shared__ __align__(16) float Bs[BK][BN];

  const int tid = threadIdx.x;
  const int tx = tid & 15;   // col dir
  const int ty = tid >> 4;   // row dir
  const int bm0 = blockIdx.x * BM;
  const int bn0 = blockIdx.y * BN;
  const int gate = bn0 >> 9;  // BN=64 tiles never straddle a gate boundary

  // A-tile load assignment: 64 rows x 16 k, one float4 per thread
  const int a_b = tid >> 2;
  const int a_k = (tid & 3) << 2;
  // B-tile load assignment: 16 k x 64 n, one float4 per thread
  const int b_k = tid >> 4;
  const int b_n = (tid & 15) << 2;

  float acc[4][4] = {};

  // ---- segment 1: masked input @ W ----
  const float* mbase = mask + (size_t)gate * BATCH * Kin;
  for (int k0 = 0; k0 < Kin; k0 += BK) {
    float4 av = make_float4(0.f, 0.f, 0.f, 0.f);
    const int ka = k0 + a_k;
    if (ka < Kin) {
      const int b = bm0 + a_b;
      const float* arow =
          A1 ? (A1 + (size_t)b * Kin)
             : (embed + (size_t)inputs[b * TT + t] * EMB);
      av = *(const float4*)(arow + ka);
      float4 mv = *(const float4*)(mbase + (size_t)b * Kin + ka);
      av.x *= mv.x; av.y *= mv.y; av.z *= mv.z; av.w *= mv.w;
    }
    As[a_k + 0][a_b] = av.x;
    As[a_k + 1][a_b] = av.y;
    As[a_k + 2][a_b] = av.z;
    As[a_k + 3][a_b] = av.w;

    float4 bv = make_float4(0.f, 0.f, 0.f, 0.f);
    const int kb = k0 + b_k;
    if (kb < Kin) bv = *(const float4*)(W + (size_t)kb * N4 + bn0 + b_n);
    *(float4*)&Bs[b_k][b_n] = bv;

    __syncthreads();
#pragma unroll
    for (int p = 0; p < BK; p++) {
      const float4 a = *(const float4*)&As[p][ty << 2];
      const float4 w = *(const float4*)&Bs[p][tx << 2];
      acc[0][0] += a.x * w.x; acc[0][1] += a.x * w.y; acc[0][2] += a.x * w.z; acc[0][3] += a.x * w.w;
      acc[1][0] += a.y * w.x; acc[1][1] += a.y * w.y; acc[1][2] += a.y * w.z; acc[1][3] += a.y * w.w;
      acc[2][0] += a.z * w.x; acc[2][1] += a.z * w.y; acc[2][2] += a.z * w.z; acc[2][3] += a.z * w.w;
      acc[3][0] += a.w * w.x; acc[3][1] += a.w * w.y; acc[3][2] += a.w * w.z; acc[3][3] += a.w * w.w;
    }
    __syncthreads();
  }

  // ---- segment 2: h_prev @ U (K = 512, all loads full) ----
  for (int k0 = 0; k0 < UNITS; k0 += BK) {
    const int b = bm0 + a_b;
    float4 av = *(const float4*)(hprev + (size_t)b * UNITS + k0 + a_k);
    As[a_k + 0][a_b] = av.x;
    As[a_k + 1][a_b] = av.y;
    As[a_k + 2][a_b] = av.z;
    As[a_k + 3][a_b] = av.w;

    float4 bv = *(const float4*)(U + (size_t)(k0 + b_k) * N4 + bn0 + b_n);
    *(float4*)&Bs[b_k][b_n] = bv;

    __syncthreads();
#pragma unroll
    for (int p = 0; p < BK; p++) {
      const float4 a = *(const float4*)&As[p][ty << 2];
      const float4 w = *(const float4*)&Bs[p][tx << 2];
      acc[0][0] += a.x * w.x; acc[0][1] += a.x * w.y; acc[0][2] += a.x * w.z; acc[0][3] += a.x * w.w;
      acc[1][0] += a.y * w.x; acc[1][1] += a.y * w.y; acc[1][2] += a.y * w.z; acc[1][3] += a.y * w.w;
      acc[2][0] += a.z * w.x; acc[2][1] += a.z * w.y; acc[2][2] += a.z * w.z; acc[2][3] += a.z * w.w;
      acc[3][0] += a.w * w.x; acc[3][1] += a.w * w.y; acc[3][2] += a.w * w.z; acc[3][3] += a.w * w.w;
    }
    __syncthreads();
  }

  // ---- epilogue: + bias, store z ----
#pragma unroll
  for (int i = 0; i < 4; i++) {
    const int b = bm0 + (ty << 2) + i;
    const int n = bn0 + (tx << 2);
    float4 o;
    o.x = acc[i][0] + bias[n + 0];
    o.y = acc[i][1] + bias[n + 1];
    o.z = acc[i][2] + bias[n + 2];
    o.w = acc[i][3] + bias[n + 3];
    *(float4*)(z + (size_t)b * N4 + n) = o;
  }
}

// ---------------- pointwise LSTM gates (in-place h,c update) --------------
__global__ __launch_bounds__(256) void gates_kernel(const float* __restrict__ z,
                                                    float* __restrict__ h,
                                                    float* __restrict__ c) {
  const int i = blockIdx.x * blockDim.x + threadIdx.x;
  if (i >= BATCH * UNITS) return;
  const int b = i >> 9;
  const int hh = i & 511;
  const float* zb = z + (size_t)b * N4;
  const float zi = zb[hh];
  const float zf = zb[512 + hh];
  const float zg = zb[1024 + hh];
  const float zo = zb[1536 + hh];
  const float iv = 1.f / (1.f + expf(-zi));
  const float fv = 1.f / (1.f + expf(-zf));
  const float gv = tanhf(zg);
  const float ov = 1.f / (1.f + expf(-zo));
  const float cn = fv * c[i] + iv * gv;
  c[i] = cn;
  h[i] = ov * tanhf(cn);
}

// ---------------- final projection: sigmoid(h1 @ Wout + bout) -------------
__global__ __launch_bounds__(256) void out_kernel(const float* __restrict__ h1,
                                                  const float* __restrict__ Wout,
                                                  const float* __restrict__ bout,
                                                  float* __restrict__ out) {
  const int wid = (blockIdx.x * blockDim.x + threadIdx.x) >> 6;  // one wave per row
  const int lane = threadIdx.x & 63;
  if (wid >= BATCH) return;
  const float* hr = h1 + (size_t)wid * UNITS;
  float s = 0.f;
#pragma unroll
  for (int j = 0; j < UNITS; j += 64) s += hr[j + lane] * Wout[j + lane];
  for (int off = 32; off; off >>= 1) s += __shfl_down(s, off, 64);
  if (lane == 0) out[wid] = 1.f / (1.f + expf(-(s + bout[0])));
}

// --------------------------------------------------------------------------
extern "C" void kernel_launch(void* const* d_in, const int* in_sizes, int n_in,
                              void* d_out, int out_size, void* d_ws, size_t ws_size,
                              hipStream_t stream) {
  const int* inputs = (const int*)d_in[0];
  const float* embed = (const float*)d_in[1];
  const float* W0 = (const float*)d_in[2];
  const float* U0 = (const float*)d_in[3];
  const float* b0 = (const float*)d_in[4];
  const float* W1 = (const float*)d_in[5];
  const float* U1 = (const float*)d_in[6];
  const float* b1 = (const float*)d_in[7];
  const float* Wout = (const float*)d_in[8];
  const float* bout = (const float*)d_in[9];
  float* out = (float*)d_out;

  float* ws = (float*)d_ws;
  float* m0 = ws;                                   // [4][B][100]
  float* m1 = m0 + (size_t)M0N;                     // [4][B][512]
  float* h0 = m1 + (size_t)M1N;                     // [B][512] x4 (contiguous)
  float* c0 = h0 + (size_t)BATCH * UNITS;
  float* h1 = c0 + (size_t)BATCH * UNITS;
  float* c1 = h1 + (size_t)BATCH * UNITS;
  float* z  = c1 + (size_t)BATCH * UNITS;           // [B][2048]

  // zero h0,c0,h1,c1 (ws is poisoned 0xAA before every call)
  hipMemsetAsync(h0, 0, sizeof(float) * 4 * BATCH * UNITS, stream);

  masks_kernel<<<2048, 256, 0, stream>>>(m0, m1);

  const dim3 grid(BATCH / BM, N4 / BN);
  for (int t = 0; t < TT; t++) {
    // layer 0: x from embed gather, Kin=100, state (h0,c0)
    cell_gemm<<<grid, 256, 0, stream>>>(nullptr, inputs, embed, t, EMB, m0, W0,
                                        U0, b0, h0, z);
    gates_kernel<<<(BATCH * UNITS) / 256, 256, 0, stream>>>(z, h0, c0);
    // layer 1: x = h0 (fresh), Kin=512, state (h1,c1)
    cell_gemm<<<grid, 256, 0, stream>>>(h0, nullptr, nullptr, 0, UNITS, m1, W1,
                                        U1, b1, h1, z);
    gates_kernel<<<(BATCH * UNITS) / 256, 256, 0, stream>>>(z, h1, c1);
  }

  out_kernel<<<BATCH * 64 / 256, 256, 0, stream>>>(h1, Wout, bout, out);
}

// Round 2
// 6031.752 us; speedup vs baseline: 6.1072x; 6.1072x over previous
//
#include <hip/hip_runtime.h>
#include <hip/hip_bf16.h>
#include <stdint.h>

#define BATCH 4096
#define TT    80
#define EMB   100
#define UNITS 512
#define N4    2048
#define K0P   128   // padded K for layer-0 input segment (EMB=100 -> 128)

typedef unsigned short ushort;
typedef unsigned char uchar;
typedef __bf16 bf16x8 __attribute__((ext_vector_type(8)));
typedef float f32x4 __attribute__((ext_vector_type(4)));

// ---------------- threefry2x32 (JAX partitionable mode, verified r1) ------
__device__ __forceinline__ uint32_t rotl32(uint32_t x, uint32_t r) {
  return (x << r) | (x >> (32u - r));
}
__device__ __forceinline__ void tf_round4(uint32_t& x0, uint32_t& x1,
                                          int r0, int r1, int r2, int r3) {
  x0 += x1; x1 = rotl32(x1, r0); x1 ^= x0;
  x0 += x1; x1 = rotl32(x1, r1); x1 ^= x0;
  x0 += x1; x1 = rotl32(x1, r2); x1 ^= x0;
  x0 += x1; x1 = rotl32(x1, r3); x1 ^= x0;
}
__device__ __forceinline__ void tf2x32(uint32_t k0, uint32_t k1,
                                       uint32_t x0, uint32_t x1,
                                       uint32_t& y0, uint32_t& y1) {
  uint32_t k2 = k0 ^ k1 ^ 0x1BD11BDAu;
  x0 += k0; x1 += k1;
  tf_round4(x0, x1, 13, 15, 26, 6);  x0 += k1; x1 += k2 + 1u;
  tf_round4(x0, x1, 17, 29, 16, 24); x0 += k2; x1 += k0 + 2u;
  tf_round4(x0, x1, 13, 15, 26, 6);  x0 += k0; x1 += k1 + 3u;
  tf_round4(x0, x1, 17, 29, 16, 24); x0 += k1; x1 += k2 + 4u;
  tf_round4(x0, x1, 13, 15, 26, 6);  x0 += k2; x1 += k0 + 5u;
  y0 = x0; y1 = x1;
}
__device__ __forceinline__ int keepbit(uint32_t u) {
  float f = __uint_as_float((u >> 9) | 0x3F800000u) - 1.0f;
  return f < 0.8f ? 1 : 0;
}

__device__ __forceinline__ ushort f2bf(float f) {
  uint32_t u = __float_as_uint(f);
  uint32_t r = (u + 0x7FFFu + ((u >> 16) & 1u)) >> 16;
  return (ushort)r;
}
__device__ __forceinline__ float bf2f(ushort u) {
  return __uint_as_float(((uint32_t)u) << 16);
}

#define M0N (4 * BATCH * EMB)
#define M1N (4 * BATCH * UNITS)

// packed masks: m0p[b*100+k] bits g=0..3 ; m1p[b*512+h] bits g=0..3
__global__ __launch_bounds__(256) void masks_kernel(uchar* __restrict__ m0p,
                                                    uchar* __restrict__ m1p) {
  uint32_t k0a, k0b, k1a, k1b;
  tf2x32(0u, 42u, 0u, 0u, k0a, k0b);
  tf2x32(0u, 42u, 0u, 1u, k1a, k1b);
  const int n0 = BATCH * EMB;          // 409600
  const int n1 = BATCH * UNITS;        // 2097152
  const int total = n0 + n1;
  for (int i = blockIdx.x * blockDim.x + threadIdx.x; i < total;
       i += gridDim.x * blockDim.x) {
    if (i < n0) {
      uchar byte = 0;
#pragma unroll
      for (int g = 0; g < 4; g++) {
        uint32_t y0, y1;
        tf2x32(k0a, k0b, 0u, (uint32_t)(g * n0 + i), y0, y1);
        byte |= keepbit(y0 ^ y1) << g;
      }
      m0p[i] = byte;
    } else {
      int j = i - n0;
      uchar byte = 0;
#pragma unroll
      for (int g = 0; g < 4; g++) {
        uint32_t y0, y1;
        tf2x32(k1a, k1b, 0u, (uint32_t)(g * n1 + j), y0, y1);
        byte |= keepbit(y0 ^ y1) << g;
      }
      m1p[j] = byte;
    }
  }
}

// ---------------- weight convert+transpose: src[K][2048] f32 -> dst[2048][Kpad] bf16
__global__ __launch_bounds__(256) void convT(const float* __restrict__ src,
                                             ushort* __restrict__ dst,
                                             int Ksrc, int Kpad) {
  __shared__ float t[32][33];
  const int n0 = blockIdx.x * 32, kk0 = blockIdx.y * 32;
  const int tx = threadIdx.x & 31, ty = threadIdx.x >> 5;
#pragma unroll
  for (int r = ty; r < 32; r += 8) {
    const int k = kk0 + r;
    t[r][tx] = (k < Ksrc) ? src[(size_t)k * N4 + n0 + tx] : 0.f;
  }
  __syncthreads();
#pragma unroll
  for (int r = ty; r < 32; r += 8)
    dst[(size_t)(n0 + r) * Kpad + kk0 + tx] = f2bf(t[tx][r]);
}

// ---------------- Xm0 prep for timestep t (per-gate masked embed, bf16, padded)
__device__ __forceinline__ void xm0_prep_one(int i, int t,
                                             const int* __restrict__ inputs,
                                             const float* __restrict__ embed,
                                             const uchar* __restrict__ m0p,
                                             ushort* __restrict__ Xm0) {
  const int k = i & 127;
  const int b = (i >> 7) & 4095;
  const int g = i >> 19;
  float v = 0.f;
  if (k < EMB) {
    const int idx = inputs[b * TT + t];
    const float e = embed[(size_t)idx * EMB + k];
    v = ((m0p[b * EMB + k] >> g) & 1) ? e * 1.25f : 0.f;
  }
  Xm0[((size_t)g << 19) + (b << 7) + k] = f2bf(v);
}

__global__ __launch_bounds__(256) void prep0_kernel(const int* __restrict__ inputs,
                                                    const float* __restrict__ embed,
                                                    const uchar* __restrict__ m0p,
                                                    ushort* __restrict__ Xm0) {
  const int i = blockIdx.x * blockDim.x + threadIdx.x;
  xm0_prep_one(i, 0, inputs, embed, m0p, Xm0);
}

// ---------------- MFMA GEMM: z = A1g@B1^T + A2@B2^T + bias --------------
// A1: [4][4096][K1] bf16 (per-gate), B1: [2048][K1] bf16 (transposed weights)
// A2: [4096][512] bf16, B2: [2048][512] bf16, z: [4096][2048] f32
__device__ __forceinline__ void gload16(const void* g, void* l) {
  __builtin_amdgcn_global_load_lds(
      (const __attribute__((address_space(1))) unsigned int*)g,
      (__attribute__((address_space(3))) unsigned int*)l, 16, 0, 0);
}

__global__ __launch_bounds__(256) void cell_gemm_mfma(
    const ushort* __restrict__ A1, int K1,
    const ushort* __restrict__ B1,
    const ushort* __restrict__ A2,
    const ushort* __restrict__ B2,
    const float* __restrict__ bias,
    float* __restrict__ z) {
  __shared__ __align__(16) ushort As[128 * 32];
  __shared__ __align__(16) ushort Bs[128 * 32];

  const int tid = threadIdx.x;
  const int w = tid >> 6, l = tid & 63;
  const int bm0 = blockIdx.x * 128, bn0 = blockIdx.y * 128;
  const int gate = bn0 >> 9;
  const int wm = (w >> 1) * 64, wn = (w & 1) * 64;
  const int fr = l & 15, kq = l >> 4;      // frag row, k-quad
  const int schunk = (l & 3) * 8;          // staging chunk (bf16 elems)
  const int srow_l = l >> 2;               // staging row within 16

  f32x4 acc[4][4] = {};

  const ushort* A1g = A1 + (size_t)gate * BATCH * K1;

#pragma unroll 1
  for (int seg = 0; seg < 2; seg++) {
    const ushort* A = seg ? A2 : A1g;
    const ushort* B = seg ? B2 : B1;
    const int K = seg ? UNITS : K1;
#pragma unroll 1
    for (int k0 = 0; k0 < K; k0 += 32) {
#pragma unroll
      for (int c2 = 0; c2 < 2; c2++) {
        const int r = (w * 2 + c2) * 16 + srow_l;
        gload16(A + (size_t)(bm0 + r) * K + k0 + schunk,
                (void*)(As + (w * 2 + c2) * 512));
        gload16(B + (size_t)(bn0 + r) * K + k0 + schunk,
                (void*)(Bs + (w * 2 + c2) * 512));
      }
      __syncthreads();
      bf16x8 a[4], b[4];
#pragma unroll
      for (int f = 0; f < 4; f++) {
        a[f] = *(const bf16x8*)&As[(wm + f * 16 + fr) * 32 + kq * 8];
        b[f] = *(const bf16x8*)&Bs[(wn + f * 16 + fr) * 32 + kq * 8];
      }
#pragma unroll
      for (int fi = 0; fi < 4; fi++)
#pragma unroll
        for (int fj = 0; fj < 4; fj++)
          acc[fi][fj] = __builtin_amdgcn_mfma_f32_16x16x32_bf16(
              a[fi], b[fj], acc[fi][fj], 0, 0, 0);
      __syncthreads();
    }
  }

  // epilogue: C/D mapping col = l&15 (n), row = (l>>4)*4 + j (m)
#pragma unroll
  for (int fi = 0; fi < 4; fi++) {
#pragma unroll
    for (int fj = 0; fj < 4; fj++) {
      const int n = bn0 + wn + fj * 16 + fr;
      const float bv = bias[n];
#pragma unroll
      for (int j = 0; j < 4; j++) {
        const int m = bm0 + wm + fi * 16 + kq * 4 + j;
        z[(size_t)m * N4 + n] = acc[fi][fj][j] + bv;
      }
    }
  }
}

// ---------------- gates for layer 0: updates c0, writes h0b + H0m --------
__global__ __launch_bounds__(256) void gates0_kernel(
    const float* __restrict__ z, float* __restrict__ c0,
    ushort* __restrict__ h0b, ushort* __restrict__ H0m,
    const uchar* __restrict__ m1p) {
  const int i = blockIdx.x * blockDim.x + threadIdx.x;
  const int b = i >> 9, h = i & 511;
  const float* zb = z + (size_t)b * N4;
  const float zi = zb[h], zf = zb[512 + h], zg = zb[1024 + h], zo = zb[1536 + h];
  const float iv = 1.f / (1.f + __expf(-zi));
  const float fv = 1.f / (1.f + __expf(-zf));
  const float gv = tanhf(zg);
  const float ov = 1.f / (1.f + __expf(-zo));
  const float cn = fv * c0[i] + iv * gv;
  c0[i] = cn;
  const float hn = ov * tanhf(cn);
  h0b[i] = f2bf(hn);
  const uchar mb = m1p[i];
  const float hm = hn * 1.25f;
#pragma unroll
  for (int g = 0; g < 4; g++)
    H0m[(size_t)g * (BATCH * UNITS) + i] = f2bf((mb >> g) & 1 ? hm : 0.f);
}

// ---------------- gates for layer 1: updates c1, writes h1b; preps Xm0 ---
__global__ __launch_bounds__(256) void gates1_kernel(
    const float* __restrict__ z, float* __restrict__ c1,
    ushort* __restrict__ h1b,
    const int* __restrict__ inputs, const float* __restrict__ embed,
    const uchar* __restrict__ m0p, ushort* __restrict__ Xm0, int tnext) {
  const int i = blockIdx.x * blockDim.x + threadIdx.x;
  const int b = i >> 9, h = i & 511;
  const float* zb = z + (size_t)b * N4;
  const float zi = zb[h], zf = zb[512 + h], zg = zb[1024 + h], zo = zb[1536 + h];
  const float iv = 1.f / (1.f + __expf(-zi));
  const float fv = 1.f / (1.f + __expf(-zf));
  const float gv = tanhf(zg);
  const float ov = 1.f / (1.f + __expf(-zo));
  const float cn = fv * c1[i] + iv * gv;
  c1[i] = cn;
  h1b[i] = f2bf(ov * tanhf(cn));
  if (tnext < TT) xm0_prep_one(i, tnext, inputs, embed, m0p, Xm0);
}

// ---------------- final projection ---------------------------------------
__global__ __launch_bounds__(256) void out_kernel(const ushort* __restrict__ h1b,
                                                  const float* __restrict__ Wout,
                                                  const float* __restrict__ bout,
                                                  float* __restrict__ out) {
  const int wid = (blockIdx.x * blockDim.x + threadIdx.x) >> 6;
  const int lane = threadIdx.x & 63;
  if (wid >= BATCH) return;
  const ushort* hr = h1b + (size_t)wid * UNITS;
  float s = 0.f;
#pragma unroll
  for (int j = 0; j < UNITS; j += 64) s += bf2f(hr[j + lane]) * Wout[j + lane];
  for (int off = 32; off; off >>= 1) s += __shfl_down(s, off, 64);
  if (lane == 0) out[wid] = 1.f / (1.f + __expf(-(s + bout[0])));
}

// --------------------------------------------------------------------------
extern "C" void kernel_launch(void* const* d_in, const int* in_sizes, int n_in,
                              void* d_out, int out_size, void* d_ws, size_t ws_size,
                              hipStream_t stream) {
  const int* inputs = (const int*)d_in[0];
  const float* embed = (const float*)d_in[1];
  const float* W0 = (const float*)d_in[2];
  const float* U0 = (const float*)d_in[3];
  const float* b0 = (const float*)d_in[4];
  const float* W1 = (const float*)d_in[5];
  const float* U1 = (const float*)d_in[6];
  const float* b1 = (const float*)d_in[7];
  const float* Wout = (const float*)d_in[8];
  const float* bout = (const float*)d_in[9];
  float* out = (float*)d_out;

  char* ws = (char*)d_ws;
  float* z    = (float*)(ws + 0);                 // 33,554,432 B
  float* c0   = (float*)(ws + 33554432);          //  8,388,608
  float* c1   = (float*)(ws + 41943040);          //  8,388,608
  ushort* h0b = (ushort*)(ws + 50331648);         //  4,194,304
  ushort* h1b = (ushort*)(ws + 54525952);         //  4,194,304
  ushort* H0m = (ushort*)(ws + 58720256);         // 16,777,216
  ushort* Xm0 = (ushort*)(ws + 75497472);         //  4,194,304
  ushort* W0T = (ushort*)(ws + 79691776);         //    524,288  [2048][128]
  ushort* U0T = (ushort*)(ws + 80216064);         //  2,097,152  [2048][512]
  ushort* W1T = (ushort*)(ws + 82313216);         //  2,097,152
  ushort* U1T = (ushort*)(ws + 84410368);         //  2,097,152
  uchar* m0p  = (uchar*)(ws + 86507520);          //    409,600
  uchar* m1p  = (uchar*)(ws + 86917120);          //  2,097,152

  // zero c0,c1,h0b,h1b in one contiguous memset
  hipMemsetAsync(ws + 33554432, 0, 25165824, stream);

  masks_kernel<<<2048, 256, 0, stream>>>(m0p, m1p);

  // weight transposes (fp32 -> bf16, [N][Kpad])
  {
    dim3 g0(N4 / 32, K0P / 32);
    convT<<<g0, 256, 0, stream>>>(W0, W0T, EMB, K0P);
    dim3 g1(N4 / 32, UNITS / 32);
    convT<<<g1, 256, 0, stream>>>(U0, U0T, UNITS, UNITS);
    convT<<<g1, 256, 0, stream>>>(W1, W1T, UNITS, UNITS);
    convT<<<g1, 256, 0, stream>>>(U1, U1T, UNITS, UNITS);
  }

  prep0_kernel<<<(4 * BATCH * K0P) / 256, 256, 0, stream>>>(inputs, embed, m0p, Xm0);

  const dim3 grid(BATCH / 128, N4 / 128);
  const int gblocks = (BATCH * UNITS) / 256;
  for (int t = 0; t < TT; t++) {
    cell_gemm_mfma<<<grid, 256, 0, stream>>>(Xm0, K0P, W0T, h0b, U0T, b0, z);
    gates0_kernel<<<gblocks, 256, 0, stream>>>(z, c0, h0b, H0m, m1p);
    cell_gemm_mfma<<<grid, 256, 0, stream>>>(H0m, UNITS, W1T, h1b, U1T, b1, z);
    gates1_kernel<<<gblocks, 256, 0, stream>>>(z, c1, h1b, inputs, embed, m0p,
                                               Xm0, t + 1);
  }

  out_kernel<<<BATCH * 64 / 256, 256, 0, stream>>>(h1b, Wout, bout, out);
}